// Round 15
// baseline (941.878 us; speedup 1.0000x reference)
//
#include <hip/hip_runtime.h>
#include <hip/hip_bf16.h>

// MoE: T=16384 tokens, H=1024, I=2048, E=8, K=2 (top-2, renormalized)
#define T_TOK 16384
#define H_DIM 1024
#define I_DIM 2048
#define E_NUM 8

typedef short short8 __attribute__((ext_vector_type(8)));
typedef float f32x4 __attribute__((ext_vector_type(4)));

__device__ __forceinline__ unsigned short f2bf(float f) {
  union { float f; unsigned u; } v; v.f = f;
  unsigned r = (v.u + 0x7FFFu + ((v.u >> 16) & 1u)) >> 16;
  return (unsigned short)r;
}
__device__ __forceinline__ float bf2f(unsigned short u) {
  union { unsigned u; float f; } v; v.u = ((unsigned)u) << 16;
  return v.f;
}

__device__ __forceinline__ void gload16(const void* g, void* l) {
  __builtin_amdgcn_global_load_lds(
      (const __attribute__((address_space(1))) unsigned int*)g,
      (__attribute__((address_space(3))) unsigned int*)l, 16, 0, 0);
}

#define VMCNT6() asm volatile("s_waitcnt vmcnt(6)" ::: "memory")
#define VMCNT4() asm volatile("s_waitcnt vmcnt(4)" ::: "memory")
#define VMCNT0() asm volatile("s_waitcnt vmcnt(0)" ::: "memory")
#define BAR() __builtin_amdgcn_s_barrier()
#define SCHEDFENCE() __builtin_amdgcn_sched_barrier(0)
#define PRIO1() __builtin_amdgcn_s_setprio(1)
#define PRIO0() __builtin_amdgcn_s_setprio(0)

// ---- Phase 1: fused convert x (fp32->bf16) + router logits/top-2 ----
// grid T/4, block 256 (wave per token). stride-1 lane mapping: gw coalesced.
__global__ __launch_bounds__(256) void convert_router_kernel(
    const float* __restrict__ x, const float* __restrict__ gw,
    unsigned short* __restrict__ xb,
    int* __restrict__ tke, float* __restrict__ pwv) {
  const int tid = threadIdx.x;
  const int lane = tid & 63;
  const int wv = tid >> 6;
  const int t = blockIdx.x * 4 + wv;
  const float* xr = x + (size_t)t * H_DIM;
  unsigned short* xbr = xb + (size_t)t * H_DIM;

  float acc[8] = {0.f, 0.f, 0.f, 0.f, 0.f, 0.f, 0.f, 0.f};
#pragma unroll
  for (int i = 0; i < 16; ++i) {
    const int h = i * 64 + lane;
    float xv = xr[h];
    xbr[h] = f2bf(xv);
    const float4 g0 = *(const float4*)(gw + (size_t)h * 8);
    const float4 g1 = *(const float4*)(gw + (size_t)h * 8 + 4);
    acc[0] += xv * g0.x; acc[1] += xv * g0.y;
    acc[2] += xv * g0.z; acc[3] += xv * g0.w;
    acc[4] += xv * g1.x; acc[5] += xv * g1.y;
    acc[6] += xv * g1.z; acc[7] += xv * g1.w;
  }
#pragma unroll
  for (int e = 0; e < 8; ++e) {
#pragma unroll
    for (int off = 32; off; off >>= 1) acc[e] += __shfl_xor(acc[e], off);
  }
  int e1 = 0; float l1 = acc[0];
#pragma unroll
  for (int e = 1; e < 8; ++e) if (acc[e] > l1) { l1 = acc[e]; e1 = e; }
  int first_non = (e1 == 0) ? 1 : 0;
  int e2 = first_non; float l2 = acc[first_non];
#pragma unroll
  for (int e = 0; e < 8; ++e) {
    if (e == e1 || e == first_non) continue;
    if (acc[e] > l2) { l2 = acc[e]; e2 = e; }
  }
  float r = expf(l2 - l1);
  float w1 = 1.f / (1.f + r);
  float w2 = r / (1.f + r);
  if (lane == 0) {
    pwv[2 * t] = w1;
    pwv[2 * t + 1] = w2;
    tke[t] = e1 | (e2 << 4);
  }
}

// ---- Phase 2: build per-expert lists, wave-aggregated atomics ----
__global__ __launch_bounds__(256) void build_lists_kernel(
    const int* __restrict__ tke, int* __restrict__ list, int* __restrict__ cnt) {
  const int t = blockIdx.x * 256 + threadIdx.x;
  const int lane = threadIdx.x & 63;
  const int pk = tke[t];
  const int ee[2] = {pk & 15, (pk >> 4) & 15};
#pragma unroll
  for (int phase = 0; phase < 2; ++phase) {
    const int e = ee[phase];
    const int pid = 2 * t + phase;
#pragma unroll
    for (int ex = 0; ex < E_NUM; ++ex) {
      unsigned long long mask = __ballot(e == ex);
      if (e == ex) {
        unsigned long long below = mask & ((1ull << lane) - 1ull);
        int rank = __popcll(below);
        int leader = __ffsll((unsigned long long)mask) - 1;
        int base = 0;
        if (lane == leader) base = atomicAdd(&cnt[ex], __popcll(mask));
        base = __shfl(base, leader);
        list[ex * T_TOK + base + rank] = pid;
      }
    }
  }
}

// ------- transpose+convert: src[e][K][N] fp32 -> dst[e][N][K] bf16 ----------
__global__ __launch_bounds__(256) void transpose_convert(
    const float* __restrict__ src, unsigned short* __restrict__ dst, int K, int N) {
  __shared__ float t[128][65];
  const int e = blockIdx.x, kt = blockIdx.y, nt = blockIdx.z;
  const float* s = src + (size_t)e * K * N + (size_t)(kt * 128) * N + nt * 64;
  unsigned short* d = dst + (size_t)e * N * K + (size_t)(nt * 64) * K + kt * 128;
  const int tid = threadIdx.x;
  const int lr = tid & 15, row = tid >> 4;
#pragma unroll
  for (int p = 0; p < 8; ++p) {
    int k = row + p * 16;
    float4 v = *(const float4*)(s + (size_t)k * N + lr * 4);
    t[k][lr * 4 + 0] = v.x;
    t[k][lr * 4 + 1] = v.y;
    t[k][lr * 4 + 2] = v.z;
    t[k][lr * 4 + 3] = v.w;
  }
  __syncthreads();
  const int kc = tid & 15, nr = tid >> 4;
#pragma unroll
  for (int p = 0; p < 4; ++p) {
    int n = nr + p * 16;
    short8 o;
#pragma unroll
    for (int j = 0; j < 8; ++j) o[j] = (short)f2bf(t[kc * 8 + j][n]);
    *(short8*)&d[(size_t)n * K + kc * 8] = o;
  }
}

// ------- GEMM A: h = w * silu(x@Wg) * (x@Wu), grouped by expert -------------
// 128x64 tile, BK=32. A: depth-2 gload_lds dbuf (16KB LDS). B: global->REGS
// (double-buffered, named, prefetch 1 K-step) -- halves LDS traffic.
// counted vmcnt(6) = 2 A-stage + 4 B-reg loads in flight.
// grid (I/64, E*128) n-major.
__global__ __launch_bounds__(256, 3) void gemm_gateup(
    const unsigned short* __restrict__ xb, const unsigned short* __restrict__ wgt,
    const unsigned short* __restrict__ wut, const int* __restrict__ list,
    const int* __restrict__ cnt, const float* __restrict__ pwv,
    unsigned short* __restrict__ hbuf) {
  __shared__ unsigned short As[2][128 * 32];  // 16 KB
  __shared__ int rows_s[128];
  __shared__ float pws[128];

  const int tid = threadIdx.x;
  const int e = blockIdx.y >> 7;
  const int mt = blockIdx.y & 127;
  const int ce = cnt[e];
  if (mt * 128 >= ce) return;
  const int n0 = blockIdx.x * 64;

  if (tid < 128) {
    int idx = mt * 128 + tid;
    int pid = list[e * T_TOK + (idx < ce ? idx : 0)];
    rows_s[tid] = pid;
    pws[tid] = pwv[pid];
  }
  __syncthreads();

  // A staging (swizzled, as proven): 512 chunks, 2/thread
  const int s0 = tid, s1 = 256 + tid;
  const int q0 = (((s0 & 3) ^ ((s0 >> 3) & 3)) * 8);
  const int q1 = (((s1 & 3) ^ ((s1 >> 3) & 3)) * 8);
  const int tok0 = rows_s[s0 >> 2] >> 1, tok1 = rows_s[s1 >> 2] >> 1;
  const unsigned short* a_src0 = xb + (size_t)tok0 * H_DIM + q0;
  const unsigned short* a_src1 = xb + (size_t)tok1 * H_DIM + q1;

#define STAGE_A(b, k0)                          \
  do {                                          \
    gload16(a_src0 + (k0), &As[b][s0 * 8]);     \
    gload16(a_src1 + (k0), &As[b][s1 * 8]);     \
  } while (0)

  const int lane = tid & 63;
  const int wv = tid >> 6;
  const int wr = (wv >> 1) * 64;   // 2 row-groups of 64 (BM=128)
  const int wc = (wv & 1) * 32;    // 2 col-groups of 32 (BN=64)
  const int lr = lane & 15;
  const int lg = lane >> 4;
  const int lks = ((lg ^ ((lr >> 1) & 3)) * 8);  // A swizzled k-slot

  // B fragment pointers: row (n0+wc+nf*16+lr), k-bytes lg*16 within K-chunk.
  // Matches the logical fragment the old swizzled-LDS path delivered.
  const unsigned short* bg0p = wgt + ((size_t)e * I_DIM + n0 + wc + lr) * H_DIM + lg * 8;
  const unsigned short* bg1p = bg0p + (size_t)16 * H_DIM;
  const unsigned short* bu0p = wut + ((size_t)e * I_DIM + n0 + wc + lr) * H_DIM + lg * 8;
  const unsigned short* bu1p = bu0p + (size_t)16 * H_DIM;

  f32x4 zero = {0.f, 0.f, 0.f, 0.f};
  f32x4 accg[4][2], accu[4][2];
#pragma unroll
  for (int m = 0; m < 4; ++m)
#pragma unroll
    for (int n = 0; n < 2; ++n) { accg[m][n] = zero; accu[m][n] = zero; }

  // prologue: stage A(0), load B(0) into the "A-role" regs
  STAGE_A(0, 0);
  short8 bgA0 = *(const short8*)(bg0p);
  short8 bgA1 = *(const short8*)(bg1p);
  short8 buA0 = *(const short8*)(bu0p);
  short8 buA1 = *(const short8*)(bu1p);
  short8 bgB0, bgB1, buB0, buB1;

#define GU_MFMA(BG0, BG1, BU0, BU1, AB)                                        \
  do {                                                                         \
    short8 a_[4];                                                              \
    _Pragma("unroll") for (int m = 0; m < 4; ++m)                              \
        a_[m] = *(const short8*)&(AB)[(wr + m * 16 + lr) * 32 + lks];          \
    PRIO1();                                                                   \
    _Pragma("unroll") for (int m = 0; m < 4; ++m) {                            \
      accg[m][0] = __builtin_amdgcn_mfma_f32_16x16x32_bf16(a_[m], BG0, accg[m][0], 0, 0, 0); \
      accg[m][1] = __builtin_amdgcn_mfma_f32_16x16x32_bf16(a_[m], BG1, accg[m][1], 0, 0, 0); \
      accu[m][0] = __builtin_amdgcn_mfma_f32_16x16x32_bf16(a_[m], BU0, accu[m][0], 0, 0, 0); \
      accu[m][1] = __builtin_amdgcn_mfma_f32_16x16x32_bf16(a_[m], BU1, accu[m][1], 0, 0, 0); \
    }                                                                          \
    PRIO0();                                                                   \
  } while (0)

  // 32 K-steps, unrolled x2 so B reg double-buffer has static names
  for (int kt2 = 0; kt2 < 16; ++kt2) {
    const int kt = kt2 * 2;
    {  // even step: compute buf0 + B(A-regs); prefetch A(kt+1)->buf1, B(kt+1)->B-regs
      const int k1 = (kt + 1) * 32;
      STAGE_A(1, k1);
      bgB0 = *(const short8*)(bg0p + k1);
      bgB1 = *(const short8*)(bg1p + k1);
      buB0 = *(const short8*)(bu0p + k1);
      buB1 = *(const short8*)(bu1p + k1);
      VMCNT6();   // A(kt) in LDS, B(kt) in regs; 6 just-issued still in flight
      BAR();
      SCHEDFENCE();
      GU_MFMA(bgA0, bgA1, buA0, buA1, As[0]);
      BAR();
    }
    {  // odd step: compute buf1 + B(B-regs); prefetch A(kt+2)->buf0, B(kt+2)->A-regs
      if (kt2 < 15) {
        const int k2 = (kt + 2) * 32;
        STAGE_A(0, k2);
        bgA0 = *(const short8*)(bg0p + k2);
        bgA1 = *(const short8*)(bg1p + k2);
        buA0 = *(const short8*)(bu0p + k2);
        buA1 = *(const short8*)(bu1p + k2);
        VMCNT6();
      } else {
        VMCNT0();
      }
      BAR();
      SCHEDFENCE();
      GU_MFMA(bgB0, bgB1, buB0, buB1, As[1]);
      BAR();
    }
  }
#undef GU_MFMA
#undef STAGE_A

  const int rr = lg * 4;
#pragma unroll
  for (int m = 0; m < 4; ++m) {
#pragma unroll
    for (int j = 0; j < 4; ++j) {
      int tr = wr + m * 16 + rr + j;
      if (mt * 128 + tr < ce) {
        int pid = rows_s[tr];
        float wgt_r = pws[tr];
        size_t rowb = (size_t)pid * I_DIM + n0 + wc;
#pragma unroll
        for (int n = 0; n < 2; ++n) {
          float g = accg[m][n][j];
          float u = accu[m][n][j];
          float hv = wgt_r * (g / (1.f + __expf(-g))) * u;
          hbuf[rowb + n * 16 + lr] = f2bf(hv);
        }
      }
    }
  }
}

// ---------------- GEMM B: pbuf[pid] = h[pid] @ Wd, grouped by expert --------
// 128x128 tile, BK=32, 3-deep LDS ring, counted vmcnt. grid (H/128, E*128)
// [R10 proven]
__global__ __launch_bounds__(256, 3) void gemm_down(
    const unsigned short* __restrict__ hbuf, const unsigned short* __restrict__ wdt,
    const int* __restrict__ list, const int* __restrict__ cnt,
    unsigned short* __restrict__ pbuf) {
  __shared__ unsigned short As[3][128 * 32];
  __shared__ unsigned short Bs[3][128 * 32];
  __shared__ int rows_s[128];

  const int tid = threadIdx.x;
  const int e = blockIdx.y >> 7;
  const int mt = blockIdx.y & 127;
  const int ce = cnt[e];
  if (mt * 128 >= ce) return;
  const int n0 = blockIdx.x * 128;

  if (tid < 128) {
    int idx = mt * 128 + tid;
    rows_s[tid] = list[e * T_TOK + (idx < ce ? idx : 0)];
  }
  __syncthreads();

  const int s0 = tid, s1 = 256 + tid;
  const int r0s = s0 >> 2, r1s = s1 >> 2;
  const int q0 = (((s0 & 3) ^ ((s0 >> 3) & 3)) * 8);
  const int q1 = (((s1 & 3) ^ ((s1 >> 3) & 3)) * 8);
  const int pid0 = rows_s[r0s], pid1 = rows_s[r1s];

  const unsigned short* wd_base = wdt + ((size_t)e * H_DIM + n0) * I_DIM;
  const unsigned short* a_src0 = hbuf + (size_t)pid0 * I_DIM + q0;
  const unsigned short* a_src1 = hbuf + (size_t)pid1 * I_DIM + q1;
  const unsigned short* b_src0 = wd_base + (size_t)r0s * I_DIM + q0;
  const unsigned short* b_src1 = wd_base + (size_t)r1s * I_DIM + q1;

#define STAGE_DN(b, k0)                         \
  do {                                          \
    gload16(a_src0 + (k0), &As[b][s0 * 8]);     \
    gload16(a_src1 + (k0), &As[b][s1 * 8]);     \
    gload16(b_src0 + (k0), &Bs[b][s0 * 8]);     \
    gload16(b_src1 + (k0), &Bs[b][s1 * 8]);     \
  } while (0)

  f32x4 zero = {0.f, 0.f, 0.f, 0.f};
  f32x4 acc[4][4];
#pragma unroll
  for (int m = 0; m < 4; ++m)
#pragma unroll
    for (int n = 0; n < 4; ++n) acc[m][n] = zero;

  const int lane = tid & 63;
  const int wv = tid >> 6;
  const int wr = (wv >> 1) * 64;
  const int wc = (wv & 1) * 64;
  const int lr = lane & 15;
  const int lks = (((lane >> 4) ^ ((lr >> 1) & 3)) * 8);

  STAGE_DN(0, 0);
  STAGE_DN(1, 32);

  int rb = 0;
  for (int kt = 0; kt < I_DIM / 32; ++kt) {
    if (kt < I_DIM / 32 - 1) VMCNT4(); else VMCNT0();
    BAR();
    SCHEDFENCE();
    if (kt + 2 < I_DIM / 32) {
      int sb = rb + 2; if (sb >= 3) sb -= 3;
      STAGE_DN(sb, (kt + 2) * 32);
    }
    const unsigned short* Ab = As[rb];
    const unsigned short* Bb = Bs[rb];
    short8 a[4], b[4];
#pragma unroll
    for (int m = 0; m < 4; ++m)
      a[m] = *(const short8*)&Ab[(wr + m * 16 + lr) * 32 + lks];
#pragma unroll
    for (int n = 0; n < 4; ++n)
      b[n] = *(const short8*)&Bb[(wc + n * 16 + lr) * 32 + lks];
    PRIO1();
#pragma unroll
    for (int m = 0; m < 4; ++m)
#pragma unroll
      for (int n = 0; n < 4; ++n)
        acc[m][n] = __builtin_amdgcn_mfma_f32_16x16x32_bf16(a[m], b[n], acc[m][n], 0, 0, 0);
    PRIO0();
    rb = (rb + 1 == 3) ? 0 : rb + 1;
  }
#undef STAGE_DN

  const int rr = (lane >> 4) * 4;
#pragma unroll
  for (int m = 0; m < 4; ++m) {
#pragma unroll
    for (int j = 0; j < 4; ++j) {
      int tr = wr + m * 16 + rr + j;
      if (mt * 128 + tr < ce) {
        int pid = rows_s[tr];
        unsigned short* orow = pbuf + (size_t)pid * H_DIM + n0 + wc;
#pragma unroll
        for (int n = 0; n < 4; ++n)
          orow[n * 16 + lr] = f2bf(acc[m][n][j]);
      }
    }
  }
}

// ---- combine: out[t] = pair[2t] + pair[2t+1], in-place bf16->fp32 ----------
__global__ __launch_bounds__(256) void combine_kernel(float* __restrict__ out) {
  const int tid = threadIdx.x, lane = tid & 63, wv = tid >> 6;
  const int t = blockIdx.x * 4 + wv;
  const unsigned short* p = (const unsigned short*)out;
  const unsigned short* r0 = p + (size_t)(2 * t) * H_DIM + lane * 16;
  const unsigned short* r1 = p + (size_t)(2 * t + 1) * H_DIM + lane * 16;
  short8 a0 = *(const short8*)r0;
  short8 a1 = *(const short8*)(r0 + 8);
  short8 b0 = *(const short8*)r1;
  short8 b1 = *(const short8*)(r1 + 8);
  float res[16];
#pragma unroll
  for (int j = 0; j < 8; ++j) {
    res[j] = bf2f((unsigned short)a0[j]) + bf2f((unsigned short)b0[j]);
    res[8 + j] = bf2f((unsigned short)a1[j]) + bf2f((unsigned short)b1[j]);
  }
  float* orow = out + (size_t)t * H_DIM + lane * 16;
#pragma unroll
  for (int j = 0; j < 4; ++j) {
    float4 w = {res[4 * j], res[4 * j + 1], res[4 * j + 2], res[4 * j + 3]};
    ((float4*)orow)[j] = w;
  }
}

// ---------------- launch ----------------
extern "C" void kernel_launch(void* const* d_in, const int* in_sizes, int n_in,
                              void* d_out, int out_size, void* d_ws, size_t ws_size,
                              hipStream_t stream) {
  const float* x = (const float*)d_in[0];
  const float* gw = (const float*)d_in[1];
  const float* wgf = (const float*)d_in[2];
  const float* wuf = (const float*)d_in[3];
  const float* wdf = (const float*)d_in[4];

  const size_t off_xb   = 0;
  const size_t off_wdt  = 33554432;
  const size_t off_h    = 67108864;
  const size_t off_list = 201326592;
  const size_t off_pw   = 201850880;
  const size_t off_cnt  = 201981952;
  const size_t ws_needed = off_cnt + 64;
  if (ws_size < ws_needed) return;

  char* ws = (char*)d_ws;
  unsigned short* xb   = (unsigned short*)(ws + off_xb);
  unsigned short* wdt  = (unsigned short*)(ws + off_wdt);
  unsigned short* hbuf = (unsigned short*)(ws + off_h);
  int*   list = (int*)(ws + off_list);
  float* pwv  = (float*)(ws + off_pw);
  int*   cnt  = (int*)(ws + off_cnt);
  int*   tke  = (int*)(ws + off_h);  // parks in hbuf (unused until gemm_gateup)

  unsigned short* wgt = (unsigned short*)d_out;
  unsigned short* wut = (unsigned short*)d_out + (size_t)E_NUM * H_DIM * I_DIM;
  unsigned short* pbuf = (unsigned short*)d_out;

  hipMemsetAsync(cnt, 0, E_NUM * sizeof(int), stream);

  convert_router_kernel<<<T_TOK / 4, 256, 0, stream>>>(x, gw, xb, tke, pwv);
  build_lists_kernel<<<T_TOK / 256, 256, 0, stream>>>(tke, list, cnt);
  transpose_convert<<<dim3(E_NUM, H_DIM / 128, I_DIM / 64), 256, 0, stream>>>(
      wgf, wgt, H_DIM, I_DIM);
  transpose_convert<<<dim3(E_NUM, H_DIM / 128, I_DIM / 64), 256, 0, stream>>>(
      wuf, wut, H_DIM, I_DIM);
  transpose_convert<<<dim3(E_NUM, I_DIM / 128, H_DIM / 64), 256, 0, stream>>>(
      wdf, wdt, I_DIM, H_DIM);

  gemm_gateup<<<dim3(I_DIM / 64, E_NUM * 128), 256, 0, stream>>>(
      xb, wgt, wut, list, cnt, pwv, hbuf);

  gemm_down<<<dim3(H_DIM / 128, E_NUM * 128), 256, 0, stream>>>(
      hbuf, wdt, list, cnt, pbuf);

  combine_kernel<<<T_TOK / 4, 256, 0, stream>>>((float*)d_out);
}

// Round 16
// 696.396 us; speedup vs baseline: 1.3525x; 1.3525x over previous
//
#include <hip/hip_runtime.h>
#include <hip/hip_bf16.h>

// MoE: T=16384 tokens, H=1024, I=2048, E=8, K=2 (top-2, renormalized)
#define T_TOK 16384
#define H_DIM 1024
#define I_DIM 2048
#define E_NUM 8

typedef short short8 __attribute__((ext_vector_type(8)));
typedef float f32x4 __attribute__((ext_vector_type(4)));

__device__ __forceinline__ unsigned short f2bf(float f) {
  union { float f; unsigned u; } v; v.f = f;
  unsigned r = (v.u + 0x7FFFu + ((v.u >> 16) & 1u)) >> 16;
  return (unsigned short)r;
}
__device__ __forceinline__ float bf2f(unsigned short u) {
  union { unsigned u; float f; } v; v.u = ((unsigned)u) << 16;
  return v.f;
}

__device__ __forceinline__ void gload16(const void* g, void* l) {
  __builtin_amdgcn_global_load_lds(
      (const __attribute__((address_space(1))) unsigned int*)g,
      (__attribute__((address_space(3))) unsigned int*)l, 16, 0, 0);
}

#define VMCNT4() asm volatile("s_waitcnt vmcnt(4)" ::: "memory")
#define VMCNT0() asm volatile("s_waitcnt vmcnt(0)" ::: "memory")
#define BAR() __builtin_amdgcn_s_barrier()
#define SCHEDFENCE() __builtin_amdgcn_sched_barrier(0)
#define PRIO1() __builtin_amdgcn_s_setprio(1)
#define PRIO0() __builtin_amdgcn_s_setprio(0)

// ---- Phase 1: fused convert x (fp32->bf16) + router logits/top-2 ----
// grid T/4, block 256 (wave per token). stride-1 lane mapping: gw coalesced.
__global__ __launch_bounds__(256) void convert_router_kernel(
    const float* __restrict__ x, const float* __restrict__ gw,
    unsigned short* __restrict__ xb,
    int* __restrict__ tke, float* __restrict__ pwv) {
  const int tid = threadIdx.x;
  const int lane = tid & 63;
  const int wv = tid >> 6;
  const int t = blockIdx.x * 4 + wv;
  const float* xr = x + (size_t)t * H_DIM;
  unsigned short* xbr = xb + (size_t)t * H_DIM;

  float acc[8] = {0.f, 0.f, 0.f, 0.f, 0.f, 0.f, 0.f, 0.f};
#pragma unroll
  for (int i = 0; i < 16; ++i) {
    const int h = i * 64 + lane;
    float xv = xr[h];
    xbr[h] = f2bf(xv);
    const float4 g0 = *(const float4*)(gw + (size_t)h * 8);
    const float4 g1 = *(const float4*)(gw + (size_t)h * 8 + 4);
    acc[0] += xv * g0.x; acc[1] += xv * g0.y;
    acc[2] += xv * g0.z; acc[3] += xv * g0.w;
    acc[4] += xv * g1.x; acc[5] += xv * g1.y;
    acc[6] += xv * g1.z; acc[7] += xv * g1.w;
  }
#pragma unroll
  for (int e = 0; e < 8; ++e) {
#pragma unroll
    for (int off = 32; off; off >>= 1) acc[e] += __shfl_xor(acc[e], off);
  }
  int e1 = 0; float l1 = acc[0];
#pragma unroll
  for (int e = 1; e < 8; ++e) if (acc[e] > l1) { l1 = acc[e]; e1 = e; }
  int first_non = (e1 == 0) ? 1 : 0;
  int e2 = first_non; float l2 = acc[first_non];
#pragma unroll
  for (int e = 0; e < 8; ++e) {
    if (e == e1 || e == first_non) continue;
    if (acc[e] > l2) { l2 = acc[e]; e2 = e; }
  }
  float r = expf(l2 - l1);
  float w1 = 1.f / (1.f + r);
  float w2 = r / (1.f + r);
  if (lane == 0) {
    pwv[2 * t] = w1;
    pwv[2 * t + 1] = w2;
    tke[t] = e1 | (e2 << 4);
  }
}

// ---- Phase 2: build per-expert lists, wave-aggregated atomics ----
__global__ __launch_bounds__(256) void build_lists_kernel(
    const int* __restrict__ tke, int* __restrict__ list, int* __restrict__ cnt) {
  const int t = blockIdx.x * 256 + threadIdx.x;
  const int lane = threadIdx.x & 63;
  const int pk = tke[t];
  const int ee[2] = {pk & 15, (pk >> 4) & 15};
#pragma unroll
  for (int phase = 0; phase < 2; ++phase) {
    const int e = ee[phase];
    const int pid = 2 * t + phase;
#pragma unroll
    for (int ex = 0; ex < E_NUM; ++ex) {
      unsigned long long mask = __ballot(e == ex);
      if (e == ex) {
        unsigned long long below = mask & ((1ull << lane) - 1ull);
        int rank = __popcll(below);
        int leader = __ffsll((unsigned long long)mask) - 1;
        int base = 0;
        if (lane == leader) base = atomicAdd(&cnt[ex], __popcll(mask));
        base = __shfl(base, leader);
        list[ex * T_TOK + base + rank] = pid;
      }
    }
  }
}

// ------- transpose+convert: src[e][K][N] fp32 -> dst[e][N][K] bf16 ----------
__global__ __launch_bounds__(256) void transpose_convert(
    const float* __restrict__ src, unsigned short* __restrict__ dst, int K, int N) {
  __shared__ float t[128][65];
  const int e = blockIdx.x, kt = blockIdx.y, nt = blockIdx.z;
  const float* s = src + (size_t)e * K * N + (size_t)(kt * 128) * N + nt * 64;
  unsigned short* d = dst + (size_t)e * N * K + (size_t)(nt * 64) * K + kt * 128;
  const int tid = threadIdx.x;
  const int lr = tid & 15, row = tid >> 4;
#pragma unroll
  for (int p = 0; p < 8; ++p) {
    int k = row + p * 16;
    float4 v = *(const float4*)(s + (size_t)k * N + lr * 4);
    t[k][lr * 4 + 0] = v.x;
    t[k][lr * 4 + 1] = v.y;
    t[k][lr * 4 + 2] = v.z;
    t[k][lr * 4 + 3] = v.w;
  }
  __syncthreads();
  const int kc = tid & 15, nr = tid >> 4;
#pragma unroll
  for (int p = 0; p < 4; ++p) {
    int n = nr + p * 16;
    short8 o;
#pragma unroll
    for (int j = 0; j < 8; ++j) o[j] = (short)f2bf(t[kc * 8 + j][n]);
    *(short8*)&d[(size_t)n * K + kc * 8] = o;
  }
}

// ------- GEMM A: h = w * silu(x@Wg) * (x@Wu), grouped by expert -------------
// 128x64 tile, BK=32, depth-2 dbuf (33.8KB -> 4 blocks/CU), counted vmcnt(4),
// XOR swizzle. Chunked XCD remap: each XCD owns contiguous m-blocks (A-panel
// L2 locality). grid (I/64, E*128).  [R10 proven 365us + T1]
__global__ __launch_bounds__(256, 3) void gemm_gateup(
    const unsigned short* __restrict__ xb, const unsigned short* __restrict__ wgt,
    const unsigned short* __restrict__ wut, const int* __restrict__ list,
    const int* __restrict__ cnt, const float* __restrict__ pwv,
    unsigned short* __restrict__ hbuf) {
  __shared__ unsigned short As[2][128 * 32];
  __shared__ unsigned short Bg[2][64 * 32];
  __shared__ unsigned short Bu[2][64 * 32];
  __shared__ int rows_s[128];
  __shared__ float pws[128];

  const int tid = threadIdx.x;
  // bijective chunked XCD swizzle: nwg = 32*1024 = 32768, 8 | nwg
  const int flat = blockIdx.x + 32 * blockIdx.y;
  const int sw = (flat & 7) * (32768 / 8) + (flat >> 3);
  const int ntile = sw & 31;          // 32 n-tiles
  const int mb = sw >> 5;             // 1024 m-blocks
  const int e = mb >> 7;
  const int mt = mb & 127;
  const int ce = cnt[e];
  if (mt * 128 >= ce) return;
  const int n0 = ntile * 64;

  if (tid < 128) {
    int idx = mt * 128 + tid;
    int pid = list[e * T_TOK + (idx < ce ? idx : 0)];
    rows_s[tid] = pid;
    pws[tid] = pwv[pid];
  }
  __syncthreads();

  const int s0 = tid, s1 = 256 + tid;
  const int q0 = (((s0 & 3) ^ ((s0 >> 3) & 3)) * 8);
  const int q1 = (((s1 & 3) ^ ((s1 >> 3) & 3)) * 8);
  const int tok0 = rows_s[s0 >> 2] >> 1, tok1 = rows_s[s1 >> 2] >> 1;

  const unsigned short* wg_base = wgt + ((size_t)e * I_DIM + n0) * H_DIM;
  const unsigned short* wu_base = wut + ((size_t)e * I_DIM + n0) * H_DIM;
  const unsigned short* a_src0 = xb + (size_t)tok0 * H_DIM + q0;
  const unsigned short* a_src1 = xb + (size_t)tok1 * H_DIM + q1;
  const unsigned short* g_src0 = wg_base + (size_t)(s0 >> 2) * H_DIM + q0;
  const unsigned short* u_src0 = wu_base + (size_t)(s0 >> 2) * H_DIM + q0;

#define STAGE_GU(b, k0)                         \
  do {                                          \
    gload16(a_src0 + (k0), &As[b][s0 * 8]);     \
    gload16(a_src1 + (k0), &As[b][s1 * 8]);     \
    gload16(g_src0 + (k0), &Bg[b][s0 * 8]);     \
    gload16(u_src0 + (k0), &Bu[b][s0 * 8]);     \
  } while (0)

  f32x4 zero = {0.f, 0.f, 0.f, 0.f};
  f32x4 accg[4][2], accu[4][2];
#pragma unroll
  for (int m = 0; m < 4; ++m)
#pragma unroll
    for (int n = 0; n < 2; ++n) { accg[m][n] = zero; accu[m][n] = zero; }

  const int lane = tid & 63;
  const int wv = tid >> 6;
  const int wr = (wv >> 1) * 64;
  const int wc = (wv & 1) * 32;
  const int lr = lane & 15;
  const int lks = (((lane >> 4) ^ ((lr >> 1) & 3)) * 8);

  STAGE_GU(0, 0);

  for (int kt = 0; kt < H_DIM / 32; ++kt) {
    const int cur = kt & 1;
    if (kt < H_DIM / 32 - 1) {
      STAGE_GU(cur ^ 1, (kt + 1) * 32);
      VMCNT4();
    } else {
      VMCNT0();
    }
    BAR();
    SCHEDFENCE();
    const unsigned short* Ab = As[cur];
    const unsigned short* Bgb = Bg[cur];
    const unsigned short* Bub = Bu[cur];
    short8 a[4], bg[2], bu[2];
#pragma unroll
    for (int m = 0; m < 4; ++m)
      a[m] = *(const short8*)&Ab[(wr + m * 16 + lr) * 32 + lks];
#pragma unroll
    for (int n = 0; n < 2; ++n) {
      bg[n] = *(const short8*)&Bgb[(wc + n * 16 + lr) * 32 + lks];
      bu[n] = *(const short8*)&Bub[(wc + n * 16 + lr) * 32 + lks];
    }
    PRIO1();
#pragma unroll
    for (int m = 0; m < 4; ++m)
#pragma unroll
      for (int n = 0; n < 2; ++n) {
        accg[m][n] = __builtin_amdgcn_mfma_f32_16x16x32_bf16(a[m], bg[n], accg[m][n], 0, 0, 0);
        accu[m][n] = __builtin_amdgcn_mfma_f32_16x16x32_bf16(a[m], bu[n], accu[m][n], 0, 0, 0);
      }
    PRIO0();
    BAR();
  }
#undef STAGE_GU

  const int rr = (lane >> 4) * 4;
#pragma unroll
  for (int m = 0; m < 4; ++m) {
#pragma unroll
    for (int j = 0; j < 4; ++j) {
      int tr = wr + m * 16 + rr + j;
      if (mt * 128 + tr < ce) {
        int pid = rows_s[tr];
        float wgt_r = pws[tr];
        size_t rowb = (size_t)pid * I_DIM + n0 + wc;
#pragma unroll
        for (int n = 0; n < 2; ++n) {
          float g = accg[m][n][j];
          float u = accu[m][n][j];
          float hv = wgt_r * (g / (1.f + __expf(-g))) * u;
          hbuf[rowb + n * 16 + lr] = f2bf(hv);
        }
      }
    }
  }
}

// ---------------- GEMM B: pbuf[pid] = h[pid] @ Wd, grouped by expert --------
// 128x128 tile, BK=32, 3-deep LDS ring, counted vmcnt, chunked XCD remap.
// grid (H/128, E*128)  [R10 proven + T1]
__global__ __launch_bounds__(256, 3) void gemm_down(
    const unsigned short* __restrict__ hbuf, const unsigned short* __restrict__ wdt,
    const int* __restrict__ list, const int* __restrict__ cnt,
    unsigned short* __restrict__ pbuf) {
  __shared__ unsigned short As[3][128 * 32];
  __shared__ unsigned short Bs[3][128 * 32];
  __shared__ int rows_s[128];

  const int tid = threadIdx.x;
  // bijective chunked XCD swizzle: nwg = 8*1024 = 8192, 8 | nwg
  const int flat = blockIdx.x + 8 * blockIdx.y;
  const int sw = (flat & 7) * (8192 / 8) + (flat >> 3);
  const int ntile = sw & 7;           // 8 n-tiles
  const int mb = sw >> 3;             // 1024 m-blocks
  const int e = mb >> 7;
  const int mt = mb & 127;
  const int ce = cnt[e];
  if (mt * 128 >= ce) return;
  const int n0 = ntile * 128;

  if (tid < 128) {
    int idx = mt * 128 + tid;
    rows_s[tid] = list[e * T_TOK + (idx < ce ? idx : 0)];
  }
  __syncthreads();

  const int s0 = tid, s1 = 256 + tid;
  const int r0s = s0 >> 2, r1s = s1 >> 2;
  const int q0 = (((s0 & 3) ^ ((s0 >> 3) & 3)) * 8);
  const int q1 = (((s1 & 3) ^ ((s1 >> 3) & 3)) * 8);
  const int pid0 = rows_s[r0s], pid1 = rows_s[r1s];

  const unsigned short* wd_base = wdt + ((size_t)e * H_DIM + n0) * I_DIM;
  const unsigned short* a_src0 = hbuf + (size_t)pid0 * I_DIM + q0;
  const unsigned short* a_src1 = hbuf + (size_t)pid1 * I_DIM + q1;
  const unsigned short* b_src0 = wd_base + (size_t)r0s * I_DIM + q0;
  const unsigned short* b_src1 = wd_base + (size_t)r1s * I_DIM + q1;

#define STAGE_DN(b, k0)                         \
  do {                                          \
    gload16(a_src0 + (k0), &As[b][s0 * 8]);     \
    gload16(a_src1 + (k0), &As[b][s1 * 8]);     \
    gload16(b_src0 + (k0), &Bs[b][s0 * 8]);     \
    gload16(b_src1 + (k0), &Bs[b][s1 * 8]);     \
  } while (0)

  f32x4 zero = {0.f, 0.f, 0.f, 0.f};
  f32x4 acc[4][4];
#pragma unroll
  for (int m = 0; m < 4; ++m)
#pragma unroll
    for (int n = 0; n < 4; ++n) acc[m][n] = zero;

  const int lane = tid & 63;
  const int wv = tid >> 6;
  const int wr = (wv >> 1) * 64;
  const int wc = (wv & 1) * 64;
  const int lr = lane & 15;
  const int lks = (((lane >> 4) ^ ((lr >> 1) & 3)) * 8);

  STAGE_DN(0, 0);
  STAGE_DN(1, 32);

  int rb = 0;
  for (int kt = 0; kt < I_DIM / 32; ++kt) {
    if (kt < I_DIM / 32 - 1) VMCNT4(); else VMCNT0();
    BAR();
    SCHEDFENCE();
    if (kt + 2 < I_DIM / 32) {
      int sb = rb + 2; if (sb >= 3) sb -= 3;
      STAGE_DN(sb, (kt + 2) * 32);
    }
    const unsigned short* Ab = As[rb];
    const unsigned short* Bb = Bs[rb];
    short8 a[4], b[4];
#pragma unroll
    for (int m = 0; m < 4; ++m)
      a[m] = *(const short8*)&Ab[(wr + m * 16 + lr) * 32 + lks];
#pragma unroll
    for (int n = 0; n < 4; ++n)
      b[n] = *(const short8*)&Bb[(wc + n * 16 + lr) * 32 + lks];
    PRIO1();
#pragma unroll
    for (int m = 0; m < 4; ++m)
#pragma unroll
      for (int n = 0; n < 4; ++n)
        acc[m][n] = __builtin_amdgcn_mfma_f32_16x16x32_bf16(a[m], b[n], acc[m][n], 0, 0, 0);
    PRIO0();
    rb = (rb + 1 == 3) ? 0 : rb + 1;
  }
#undef STAGE_DN

  const int rr = (lane >> 4) * 4;
#pragma unroll
  for (int m = 0; m < 4; ++m) {
#pragma unroll
    for (int j = 0; j < 4; ++j) {
      int tr = wr + m * 16 + rr + j;
      if (mt * 128 + tr < ce) {
        int pid = rows_s[tr];
        unsigned short* orow = pbuf + (size_t)pid * H_DIM + n0 + wc;
#pragma unroll
        for (int n = 0; n < 4; ++n)
          orow[n * 16 + lr] = f2bf(acc[m][n][j]);
      }
    }
  }
}

// ---- combine: out[t] = pair[2t] + pair[2t+1], in-place bf16->fp32 ----------
__global__ __launch_bounds__(256) void combine_kernel(float* __restrict__ out) {
  const int tid = threadIdx.x, lane = tid & 63, wv = tid >> 6;
  const int t = blockIdx.x * 4 + wv;
  const unsigned short* p = (const unsigned short*)out;
  const unsigned short* r0 = p + (size_t)(2 * t) * H_DIM + lane * 16;
  const unsigned short* r1 = p + (size_t)(2 * t + 1) * H_DIM + lane * 16;
  short8 a0 = *(const short8*)r0;
  short8 a1 = *(const short8*)(r0 + 8);
  short8 b0 = *(const short8*)r1;
  short8 b1 = *(const short8*)(r1 + 8);
  float res[16];
#pragma unroll
  for (int j = 0; j < 8; ++j) {
    res[j] = bf2f((unsigned short)a0[j]) + bf2f((unsigned short)b0[j]);
    res[8 + j] = bf2f((unsigned short)a1[j]) + bf2f((unsigned short)b1[j]);
  }
  float* orow = out + (size_t)t * H_DIM + lane * 16;
#pragma unroll
  for (int j = 0; j < 4; ++j) {
    float4 w = {res[4 * j], res[4 * j + 1], res[4 * j + 2], res[4 * j + 3]};
    ((float4*)orow)[j] = w;
  }
}

// ---------------- launch ----------------
extern "C" void kernel_launch(void* const* d_in, const int* in_sizes, int n_in,
                              void* d_out, int out_size, void* d_ws, size_t ws_size,
                              hipStream_t stream) {
  const float* x = (const float*)d_in[0];
  const float* gw = (const float*)d_in[1];
  const float* wgf = (const float*)d_in[2];
  const float* wuf = (const float*)d_in[3];
  const float* wdf = (const float*)d_in[4];

  const size_t off_xb   = 0;
  const size_t off_wdt  = 33554432;
  const size_t off_h    = 67108864;
  const size_t off_list = 201326592;
  const size_t off_pw   = 201850880;
  const size_t off_cnt  = 201981952;
  const size_t ws_needed = off_cnt + 64;
  if (ws_size < ws_needed) return;

  char* ws = (char*)d_ws;
  unsigned short* xb   = (unsigned short*)(ws + off_xb);
  unsigned short* wdt  = (unsigned short*)(ws + off_wdt);
  unsigned short* hbuf = (unsigned short*)(ws + off_h);
  int*   list = (int*)(ws + off_list);
  float* pwv  = (float*)(ws + off_pw);
  int*   cnt  = (int*)(ws + off_cnt);
  int*   tke  = (int*)(ws + off_h);  // parks in hbuf (unused until gemm_gateup)

  unsigned short* wgt = (unsigned short*)d_out;
  unsigned short* wut = (unsigned short*)d_out + (size_t)E_NUM * H_DIM * I_DIM;
  unsigned short* pbuf = (unsigned short*)d_out;

  hipMemsetAsync(cnt, 0, E_NUM * sizeof(int), stream);

  convert_router_kernel<<<T_TOK / 4, 256, 0, stream>>>(x, gw, xb, tke, pwv);
  build_lists_kernel<<<T_TOK / 256, 256, 0, stream>>>(tke, list, cnt);
  transpose_convert<<<dim3(E_NUM, H_DIM / 128, I_DIM / 64), 256, 0, stream>>>(
      wgf, wgt, H_DIM, I_DIM);
  transpose_convert<<<dim3(E_NUM, H_DIM / 128, I_DIM / 64), 256, 0, stream>>>(
      wuf, wut, H_DIM, I_DIM);
  transpose_convert<<<dim3(E_NUM, I_DIM / 128, H_DIM / 64), 256, 0, stream>>>(
      wdf, wdt, I_DIM, H_DIM);

  gemm_gateup<<<dim3(I_DIM / 64, E_NUM * 128), 256, 0, stream>>>(
      xb, wgt, wut, list, cnt, pwv, hbuf);

  gemm_down<<<dim3(H_DIM / 128, E_NUM * 128), 256, 0, stream>>>(
      hbuf, wdt, list, cnt, pbuf);

  combine_kernel<<<T_TOK / 4, 256, 0, stream>>>((float*)d_out);
}

// Round 17
// 670.742 us; speedup vs baseline: 1.4042x; 1.0382x over previous
//
#include <hip/hip_runtime.h>
#include <hip/hip_bf16.h>

// MoE: T=16384 tokens, H=1024, I=2048, E=8, K=2 (top-2, renormalized)
#define T_TOK 16384
#define H_DIM 1024
#define I_DIM 2048
#define E_NUM 8

typedef short short8 __attribute__((ext_vector_type(8)));
typedef float f32x4 __attribute__((ext_vector_type(4)));

__device__ __forceinline__ unsigned short f2bf(float f) {
  union { float f; unsigned u; } v; v.f = f;
  unsigned r = (v.u + 0x7FFFu + ((v.u >> 16) & 1u)) >> 16;
  return (unsigned short)r;
}
__device__ __forceinline__ float bf2f(unsigned short u) {
  union { unsigned u; float f; } v; v.u = ((unsigned)u) << 16;
  return v.f;
}

__device__ __forceinline__ void gload16(const void* g, void* l) {
  __builtin_amdgcn_global_load_lds(
      (const __attribute__((address_space(1))) unsigned int*)g,
      (__attribute__((address_space(3))) unsigned int*)l, 16, 0, 0);
}

#define VMCNT4() asm volatile("s_waitcnt vmcnt(4)" ::: "memory")
#define VMCNT0() asm volatile("s_waitcnt vmcnt(0)" ::: "memory")
#define BAR() __builtin_amdgcn_s_barrier()
#define SCHEDFENCE() __builtin_amdgcn_sched_barrier(0)
#define PRIO1() __builtin_amdgcn_s_setprio(1)
#define PRIO0() __builtin_amdgcn_s_setprio(0)

// ---- Phase 1: fused convert x (fp32->bf16) + router logits/top-2 ----
// grid T/4, block 256 (wave per token). stride-1 lane mapping: gw coalesced.
__global__ __launch_bounds__(256) void convert_router_kernel(
    const float* __restrict__ x, const float* __restrict__ gw,
    unsigned short* __restrict__ xb,
    int* __restrict__ tke, float* __restrict__ pwv) {
  const int tid = threadIdx.x;
  const int lane = tid & 63;
  const int wv = tid >> 6;
  const int t = blockIdx.x * 4 + wv;
  const float* xr = x + (size_t)t * H_DIM;
  unsigned short* xbr = xb + (size_t)t * H_DIM;

  float acc[8] = {0.f, 0.f, 0.f, 0.f, 0.f, 0.f, 0.f, 0.f};
#pragma unroll
  for (int i = 0; i < 16; ++i) {
    const int h = i * 64 + lane;
    float xv = xr[h];
    xbr[h] = f2bf(xv);
    const float4 g0 = *(const float4*)(gw + (size_t)h * 8);
    const float4 g1 = *(const float4*)(gw + (size_t)h * 8 + 4);
    acc[0] += xv * g0.x; acc[1] += xv * g0.y;
    acc[2] += xv * g0.z; acc[3] += xv * g0.w;
    acc[4] += xv * g1.x; acc[5] += xv * g1.y;
    acc[6] += xv * g1.z; acc[7] += xv * g1.w;
  }
#pragma unroll
  for (int e = 0; e < 8; ++e) {
#pragma unroll
    for (int off = 32; off; off >>= 1) acc[e] += __shfl_xor(acc[e], off);
  }
  int e1 = 0; float l1 = acc[0];
#pragma unroll
  for (int e = 1; e < 8; ++e) if (acc[e] > l1) { l1 = acc[e]; e1 = e; }
  int first_non = (e1 == 0) ? 1 : 0;
  int e2 = first_non; float l2 = acc[first_non];
#pragma unroll
  for (int e = 0; e < 8; ++e) {
    if (e == e1 || e == first_non) continue;
    if (acc[e] > l2) { l2 = acc[e]; e2 = e; }
  }
  float r = expf(l2 - l1);
  float w1 = 1.f / (1.f + r);
  float w2 = r / (1.f + r);
  if (lane == 0) {
    pwv[2 * t] = w1;
    pwv[2 * t + 1] = w2;
    tke[t] = e1 | (e2 << 4);
  }
}

// ---- Phase 2: build per-expert lists, wave-aggregated atomics ----
__global__ __launch_bounds__(256) void build_lists_kernel(
    const int* __restrict__ tke, int* __restrict__ list, int* __restrict__ cnt) {
  const int t = blockIdx.x * 256 + threadIdx.x;
  const int lane = threadIdx.x & 63;
  const int pk = tke[t];
  const int ee[2] = {pk & 15, (pk >> 4) & 15};
#pragma unroll
  for (int phase = 0; phase < 2; ++phase) {
    const int e = ee[phase];
    const int pid = 2 * t + phase;
#pragma unroll
    for (int ex = 0; ex < E_NUM; ++ex) {
      unsigned long long mask = __ballot(e == ex);
      if (e == ex) {
        unsigned long long below = mask & ((1ull << lane) - 1ull);
        int rank = __popcll(below);
        int leader = __ffsll((unsigned long long)mask) - 1;
        int base = 0;
        if (lane == leader) base = atomicAdd(&cnt[ex], __popcll(mask));
        base = __shfl(base, leader);
        list[ex * T_TOK + base + rank] = pid;
      }
    }
  }
}

// ------- transpose+convert: src[e][K][N] fp32 -> dst[e][N][K] bf16 ----------
__global__ __launch_bounds__(256) void transpose_convert(
    const float* __restrict__ src, unsigned short* __restrict__ dst, int K, int N) {
  __shared__ float t[128][65];
  const int e = blockIdx.x, kt = blockIdx.y, nt = blockIdx.z;
  const float* s = src + (size_t)e * K * N + (size_t)(kt * 128) * N + nt * 64;
  unsigned short* d = dst + (size_t)e * N * K + (size_t)(nt * 64) * K + kt * 128;
  const int tid = threadIdx.x;
  const int lr = tid & 15, row = tid >> 4;
#pragma unroll
  for (int p = 0; p < 8; ++p) {
    int k = row + p * 16;
    float4 v = *(const float4*)(s + (size_t)k * N + lr * 4);
    t[k][lr * 4 + 0] = v.x;
    t[k][lr * 4 + 1] = v.y;
    t[k][lr * 4 + 2] = v.z;
    t[k][lr * 4 + 3] = v.w;
  }
  __syncthreads();
  const int kc = tid & 15, nr = tid >> 4;
#pragma unroll
  for (int p = 0; p < 4; ++p) {
    int n = nr + p * 16;
    short8 o;
#pragma unroll
    for (int j = 0; j < 8; ++j) o[j] = (short)f2bf(t[kc * 8 + j][n]);
    *(short8*)&d[(size_t)n * K + kc * 8] = o;
  }
}

// ------- GEMM A: h = w * silu(x@Wg) * (x@Wu), grouped by expert -------------
// 128x64 tile, BK=32, depth-2 dbuf (33.8KB -> 4 blocks/CU), counted vmcnt(4),
// XOR swizzle. PLAIN n-major grid: implicit round-robin gives each XCD an
// n-slice whose weights fit its 4MB L2 (R16 showed chunked remap breaks this).
// grid (I/64, E*128).  [R14 proven 365us]
__global__ __launch_bounds__(256, 3) void gemm_gateup(
    const unsigned short* __restrict__ xb, const unsigned short* __restrict__ wgt,
    const unsigned short* __restrict__ wut, const int* __restrict__ list,
    const int* __restrict__ cnt, const float* __restrict__ pwv,
    unsigned short* __restrict__ hbuf) {
  __shared__ unsigned short As[2][128 * 32];
  __shared__ unsigned short Bg[2][64 * 32];
  __shared__ unsigned short Bu[2][64 * 32];
  __shared__ int rows_s[128];
  __shared__ float pws[128];

  const int tid = threadIdx.x;
  const int e = blockIdx.y >> 7;
  const int mt = blockIdx.y & 127;
  const int ce = cnt[e];
  if (mt * 128 >= ce) return;
  const int n0 = blockIdx.x * 64;

  if (tid < 128) {
    int idx = mt * 128 + tid;
    int pid = list[e * T_TOK + (idx < ce ? idx : 0)];
    rows_s[tid] = pid;
    pws[tid] = pwv[pid];
  }
  __syncthreads();

  const int s0 = tid, s1 = 256 + tid;
  const int q0 = (((s0 & 3) ^ ((s0 >> 3) & 3)) * 8);
  const int q1 = (((s1 & 3) ^ ((s1 >> 3) & 3)) * 8);
  const int tok0 = rows_s[s0 >> 2] >> 1, tok1 = rows_s[s1 >> 2] >> 1;

  const unsigned short* wg_base = wgt + ((size_t)e * I_DIM + n0) * H_DIM;
  const unsigned short* wu_base = wut + ((size_t)e * I_DIM + n0) * H_DIM;
  const unsigned short* a_src0 = xb + (size_t)tok0 * H_DIM + q0;
  const unsigned short* a_src1 = xb + (size_t)tok1 * H_DIM + q1;
  const unsigned short* g_src0 = wg_base + (size_t)(s0 >> 2) * H_DIM + q0;
  const unsigned short* u_src0 = wu_base + (size_t)(s0 >> 2) * H_DIM + q0;

#define STAGE_GU(b, k0)                         \
  do {                                          \
    gload16(a_src0 + (k0), &As[b][s0 * 8]);     \
    gload16(a_src1 + (k0), &As[b][s1 * 8]);     \
    gload16(g_src0 + (k0), &Bg[b][s0 * 8]);     \
    gload16(u_src0 + (k0), &Bu[b][s0 * 8]);     \
  } while (0)

  f32x4 zero = {0.f, 0.f, 0.f, 0.f};
  f32x4 accg[4][2], accu[4][2];
#pragma unroll
  for (int m = 0; m < 4; ++m)
#pragma unroll
    for (int n = 0; n < 2; ++n) { accg[m][n] = zero; accu[m][n] = zero; }

  const int lane = tid & 63;
  const int wv = tid >> 6;
  const int wr = (wv >> 1) * 64;
  const int wc = (wv & 1) * 32;
  const int lr = lane & 15;
  const int lks = (((lane >> 4) ^ ((lr >> 1) & 3)) * 8);

  STAGE_GU(0, 0);

  for (int kt = 0; kt < H_DIM / 32; ++kt) {
    const int cur = kt & 1;
    if (kt < H_DIM / 32 - 1) {
      STAGE_GU(cur ^ 1, (kt + 1) * 32);
      VMCNT4();
    } else {
      VMCNT0();
    }
    BAR();
    SCHEDFENCE();
    const unsigned short* Ab = As[cur];
    const unsigned short* Bgb = Bg[cur];
    const unsigned short* Bub = Bu[cur];
    short8 a[4], bg[2], bu[2];
#pragma unroll
    for (int m = 0; m < 4; ++m)
      a[m] = *(const short8*)&Ab[(wr + m * 16 + lr) * 32 + lks];
#pragma unroll
    for (int n = 0; n < 2; ++n) {
      bg[n] = *(const short8*)&Bgb[(wc + n * 16 + lr) * 32 + lks];
      bu[n] = *(const short8*)&Bub[(wc + n * 16 + lr) * 32 + lks];
    }
    PRIO1();
#pragma unroll
    for (int m = 0; m < 4; ++m)
#pragma unroll
      for (int n = 0; n < 2; ++n) {
        accg[m][n] = __builtin_amdgcn_mfma_f32_16x16x32_bf16(a[m], bg[n], accg[m][n], 0, 0, 0);
        accu[m][n] = __builtin_amdgcn_mfma_f32_16x16x32_bf16(a[m], bu[n], accu[m][n], 0, 0, 0);
      }
    PRIO0();
    BAR();
  }
#undef STAGE_GU

  const int rr = (lane >> 4) * 4;
#pragma unroll
  for (int m = 0; m < 4; ++m) {
#pragma unroll
    for (int j = 0; j < 4; ++j) {
      int tr = wr + m * 16 + rr + j;
      if (mt * 128 + tr < ce) {
        int pid = rows_s[tr];
        float wgt_r = pws[tr];
        size_t rowb = (size_t)pid * I_DIM + n0 + wc;
#pragma unroll
        for (int n = 0; n < 2; ++n) {
          float g = accg[m][n][j];
          float u = accu[m][n][j];
          float hv = wgt_r * (g / (1.f + __expf(-g))) * u;
          hbuf[rowb + n * 16 + lr] = f2bf(hv);
        }
      }
    }
  }
}

// ---------------- GEMM B: pbuf[pid] = h[pid] @ Wd, grouped by expert --------
// 128x128 tile, BK=32, 3-deep LDS ring, counted vmcnt, chunked XCD remap
// (R16: net positive for down). grid (H/128, E*128)
__global__ __launch_bounds__(256, 3) void gemm_down(
    const unsigned short* __restrict__ hbuf, const unsigned short* __restrict__ wdt,
    const int* __restrict__ list, const int* __restrict__ cnt,
    unsigned short* __restrict__ pbuf) {
  __shared__ unsigned short As[3][128 * 32];
  __shared__ unsigned short Bs[3][128 * 32];
  __shared__ int rows_s[128];

  const int tid = threadIdx.x;
  // bijective chunked XCD swizzle: nwg = 8*1024 = 8192, 8 | nwg
  const int flat = blockIdx.x + 8 * blockIdx.y;
  const int sw = (flat & 7) * (8192 / 8) + (flat >> 3);
  const int ntile = sw & 7;           // 8 n-tiles
  const int mb = sw >> 3;             // 1024 m-blocks
  const int e = mb >> 7;
  const int mt = mb & 127;
  const int ce = cnt[e];
  if (mt * 128 >= ce) return;
  const int n0 = ntile * 128;

  if (tid < 128) {
    int idx = mt * 128 + tid;
    rows_s[tid] = list[e * T_TOK + (idx < ce ? idx : 0)];
  }
  __syncthreads();

  const int s0 = tid, s1 = 256 + tid;
  const int r0s = s0 >> 2, r1s = s1 >> 2;
  const int q0 = (((s0 & 3) ^ ((s0 >> 3) & 3)) * 8);
  const int q1 = (((s1 & 3) ^ ((s1 >> 3) & 3)) * 8);
  const int pid0 = rows_s[r0s], pid1 = rows_s[r1s];

  const unsigned short* wd_base = wdt + ((size_t)e * H_DIM + n0) * I_DIM;
  const unsigned short* a_src0 = hbuf + (size_t)pid0 * I_DIM + q0;
  const unsigned short* a_src1 = hbuf + (size_t)pid1 * I_DIM + q1;
  const unsigned short* b_src0 = wd_base + (size_t)r0s * I_DIM + q0;
  const unsigned short* b_src1 = wd_base + (size_t)r1s * I_DIM + q1;

#define STAGE_DN(b, k0)                         \
  do {                                          \
    gload16(a_src0 + (k0), &As[b][s0 * 8]);     \
    gload16(a_src1 + (k0), &As[b][s1 * 8]);     \
    gload16(b_src0 + (k0), &Bs[b][s0 * 8]);     \
    gload16(b_src1 + (k0), &Bs[b][s1 * 8]);     \
  } while (0)

  f32x4 zero = {0.f, 0.f, 0.f, 0.f};
  f32x4 acc[4][4];
#pragma unroll
  for (int m = 0; m < 4; ++m)
#pragma unroll
    for (int n = 0; n < 4; ++n) acc[m][n] = zero;

  const int lane = tid & 63;
  const int wv = tid >> 6;
  const int wr = (wv >> 1) * 64;
  const int wc = (wv & 1) * 64;
  const int lr = lane & 15;
  const int lks = (((lane >> 4) ^ ((lr >> 1) & 3)) * 8);

  STAGE_DN(0, 0);
  STAGE_DN(1, 32);

  int rb = 0;
  for (int kt = 0; kt < I_DIM / 32; ++kt) {
    if (kt < I_DIM / 32 - 1) VMCNT4(); else VMCNT0();
    BAR();
    SCHEDFENCE();
    if (kt + 2 < I_DIM / 32) {
      int sb = rb + 2; if (sb >= 3) sb -= 3;
      STAGE_DN(sb, (kt + 2) * 32);
    }
    const unsigned short* Ab = As[rb];
    const unsigned short* Bb = Bs[rb];
    short8 a[4], b[4];
#pragma unroll
    for (int m = 0; m < 4; ++m)
      a[m] = *(const short8*)&Ab[(wr + m * 16 + lr) * 32 + lks];
#pragma unroll
    for (int n = 0; n < 4; ++n)
      b[n] = *(const short8*)&Bb[(wc + n * 16 + lr) * 32 + lks];
    PRIO1();
#pragma unroll
    for (int m = 0; m < 4; ++m)
#pragma unroll
      for (int n = 0; n < 4; ++n)
        acc[m][n] = __builtin_amdgcn_mfma_f32_16x16x32_bf16(a[m], b[n], acc[m][n], 0, 0, 0);
    PRIO0();
    rb = (rb + 1 == 3) ? 0 : rb + 1;
  }
#undef STAGE_DN

  const int rr = (lane >> 4) * 4;
#pragma unroll
  for (int m = 0; m < 4; ++m) {
#pragma unroll
    for (int j = 0; j < 4; ++j) {
      int tr = wr + m * 16 + rr + j;
      if (mt * 128 + tr < ce) {
        int pid = rows_s[tr];
        unsigned short* orow = pbuf + (size_t)pid * H_DIM + n0 + wc;
#pragma unroll
        for (int n = 0; n < 4; ++n)
          orow[n * 16 + lr] = f2bf(acc[m][n][j]);
      }
    }
  }
}

// ---- combine: out[t] = pair[2t] + pair[2t+1], in-place bf16->fp32 ----------
__global__ __launch_bounds__(256) void combine_kernel(float* __restrict__ out) {
  const int tid = threadIdx.x, lane = tid & 63, wv = tid >> 6;
  const int t = blockIdx.x * 4 + wv;
  const unsigned short* p = (const unsigned short*)out;
  const unsigned short* r0 = p + (size_t)(2 * t) * H_DIM + lane * 16;
  const unsigned short* r1 = p + (size_t)(2 * t + 1) * H_DIM + lane * 16;
  short8 a0 = *(const short8*)r0;
  short8 a1 = *(const short8*)(r0 + 8);
  short8 b0 = *(const short8*)r1;
  short8 b1 = *(const short8*)(r1 + 8);
  float res[16];
#pragma unroll
  for (int j = 0; j < 8; ++j) {
    res[j] = bf2f((unsigned short)a0[j]) + bf2f((unsigned short)b0[j]);
    res[8 + j] = bf2f((unsigned short)a1[j]) + bf2f((unsigned short)b1[j]);
  }
  float* orow = out + (size_t)t * H_DIM + lane * 16;
#pragma unroll
  for (int j = 0; j < 4; ++j) {
    float4 w = {res[4 * j], res[4 * j + 1], res[4 * j + 2], res[4 * j + 3]};
    ((float4*)orow)[j] = w;
  }
}

// ---------------- launch ----------------
extern "C" void kernel_launch(void* const* d_in, const int* in_sizes, int n_in,
                              void* d_out, int out_size, void* d_ws, size_t ws_size,
                              hipStream_t stream) {
  const float* x = (const float*)d_in[0];
  const float* gw = (const float*)d_in[1];
  const float* wgf = (const float*)d_in[2];
  const float* wuf = (const float*)d_in[3];
  const float* wdf = (const float*)d_in[4];

  const size_t off_xb   = 0;
  const size_t off_wdt  = 33554432;
  const size_t off_h    = 67108864;
  const size_t off_list = 201326592;
  const size_t off_pw   = 201850880;
  const size_t off_cnt  = 201981952;
  const size_t ws_needed = off_cnt + 64;
  if (ws_size < ws_needed) return;

  char* ws = (char*)d_ws;
  unsigned short* xb   = (unsigned short*)(ws + off_xb);
  unsigned short* wdt  = (unsigned short*)(ws + off_wdt);
  unsigned short* hbuf = (unsigned short*)(ws + off_h);
  int*   list = (int*)(ws + off_list);
  float* pwv  = (float*)(ws + off_pw);
  int*   cnt  = (int*)(ws + off_cnt);
  int*   tke  = (int*)(ws + off_h);  // parks in hbuf (unused until gemm_gateup)

  unsigned short* wgt = (unsigned short*)d_out;
  unsigned short* wut = (unsigned short*)d_out + (size_t)E_NUM * H_DIM * I_DIM;
  unsigned short* pbuf = (unsigned short*)d_out;

  hipMemsetAsync(cnt, 0, E_NUM * sizeof(int), stream);

  convert_router_kernel<<<T_TOK / 4, 256, 0, stream>>>(x, gw, xb, tke, pwv);
  build_lists_kernel<<<T_TOK / 256, 256, 0, stream>>>(tke, list, cnt);
  transpose_convert<<<dim3(E_NUM, H_DIM / 128, I_DIM / 64), 256, 0, stream>>>(
      wgf, wgt, H_DIM, I_DIM);
  transpose_convert<<<dim3(E_NUM, H_DIM / 128, I_DIM / 64), 256, 0, stream>>>(
      wuf, wut, H_DIM, I_DIM);
  transpose_convert<<<dim3(E_NUM, I_DIM / 128, H_DIM / 64), 256, 0, stream>>>(
      wdf, wdt, I_DIM, H_DIM);

  gemm_gateup<<<dim3(I_DIM / 64, E_NUM * 128), 256, 0, stream>>>(
      xb, wgt, wut, list, cnt, pwv, hbuf);

  gemm_down<<<dim3(H_DIM / 128, E_NUM * 128), 256, 0, stream>>>(
      hbuf, wdt, list, cnt, pbuf);

  combine_kernel<<<T_TOK / 4, 256, 0, stream>>>((float*)d_out);
}

// Round 18
// 670.356 us; speedup vs baseline: 1.4050x; 1.0006x over previous
//
#include <hip/hip_runtime.h>
#include <hip/hip_bf16.h>

// MoE: T=16384 tokens, H=1024, I=2048, E=8, K=2 (top-2, renormalized)
#define T_TOK 16384
#define H_DIM 1024
#define I_DIM 2048
#define E_NUM 8

typedef short short8 __attribute__((ext_vector_type(8)));
typedef float f32x4 __attribute__((ext_vector_type(4)));

__device__ __forceinline__ unsigned short f2bf(float f) {
  union { float f; unsigned u; } v; v.f = f;
  unsigned r = (v.u + 0x7FFFu + ((v.u >> 16) & 1u)) >> 16;
  return (unsigned short)r;
}
__device__ __forceinline__ float bf2f(unsigned short u) {
  union { unsigned u; float f; } v; v.u = ((unsigned)u) << 16;
  return v.f;
}

__device__ __forceinline__ void gload16(const void* g, void* l) {
  __builtin_amdgcn_global_load_lds(
      (const __attribute__((address_space(1))) unsigned int*)g,
      (__attribute__((address_space(3))) unsigned int*)l, 16, 0, 0);
}

#define VMCNT4() asm volatile("s_waitcnt vmcnt(4)" ::: "memory")
#define VMCNT0() asm volatile("s_waitcnt vmcnt(0)" ::: "memory")
#define BAR() __builtin_amdgcn_s_barrier()
#define SCHEDFENCE() __builtin_amdgcn_sched_barrier(0)
#define PRIO1() __builtin_amdgcn_s_setprio(1)
#define PRIO0() __builtin_amdgcn_s_setprio(0)

// ---- Phase 1: fused convert x (fp32->bf16) + router logits/top-2 ----
// grid T/4, block 256 (wave per token). stride-1 lane mapping: gw coalesced.
__global__ __launch_bounds__(256) void convert_router_kernel(
    const float* __restrict__ x, const float* __restrict__ gw,
    unsigned short* __restrict__ xb,
    int* __restrict__ tke, float* __restrict__ pwv) {
  const int tid = threadIdx.x;
  const int lane = tid & 63;
  const int wv = tid >> 6;
  const int t = blockIdx.x * 4 + wv;
  const float* xr = x + (size_t)t * H_DIM;
  unsigned short* xbr = xb + (size_t)t * H_DIM;

  float acc[8] = {0.f, 0.f, 0.f, 0.f, 0.f, 0.f, 0.f, 0.f};
#pragma unroll
  for (int i = 0; i < 16; ++i) {
    const int h = i * 64 + lane;
    float xv = xr[h];
    xbr[h] = f2bf(xv);
    const float4 g0 = *(const float4*)(gw + (size_t)h * 8);
    const float4 g1 = *(const float4*)(gw + (size_t)h * 8 + 4);
    acc[0] += xv * g0.x; acc[1] += xv * g0.y;
    acc[2] += xv * g0.z; acc[3] += xv * g0.w;
    acc[4] += xv * g1.x; acc[5] += xv * g1.y;
    acc[6] += xv * g1.z; acc[7] += xv * g1.w;
  }
#pragma unroll
  for (int e = 0; e < 8; ++e) {
#pragma unroll
    for (int off = 32; off; off >>= 1) acc[e] += __shfl_xor(acc[e], off);
  }
  int e1 = 0; float l1 = acc[0];
#pragma unroll
  for (int e = 1; e < 8; ++e) if (acc[e] > l1) { l1 = acc[e]; e1 = e; }
  int first_non = (e1 == 0) ? 1 : 0;
  int e2 = first_non; float l2 = acc[first_non];
#pragma unroll
  for (int e = 0; e < 8; ++e) {
    if (e == e1 || e == first_non) continue;
    if (acc[e] > l2) { l2 = acc[e]; e2 = e; }
  }
  float r = expf(l2 - l1);
  float w1 = 1.f / (1.f + r);
  float w2 = r / (1.f + r);
  if (lane == 0) {
    pwv[2 * t] = w1;
    pwv[2 * t + 1] = w2;
    tke[t] = e1 | (e2 << 4);
  }
}

// ---- Phase 2: build per-expert lists, wave-aggregated atomics ----
__global__ __launch_bounds__(256) void build_lists_kernel(
    const int* __restrict__ tke, int* __restrict__ list, int* __restrict__ cnt) {
  const int t = blockIdx.x * 256 + threadIdx.x;
  const int lane = threadIdx.x & 63;
  const int pk = tke[t];
  const int ee[2] = {pk & 15, (pk >> 4) & 15};
#pragma unroll
  for (int phase = 0; phase < 2; ++phase) {
    const int e = ee[phase];
    const int pid = 2 * t + phase;
#pragma unroll
    for (int ex = 0; ex < E_NUM; ++ex) {
      unsigned long long mask = __ballot(e == ex);
      if (e == ex) {
        unsigned long long below = mask & ((1ull << lane) - 1ull);
        int rank = __popcll(below);
        int leader = __ffsll((unsigned long long)mask) - 1;
        int base = 0;
        if (lane == leader) base = atomicAdd(&cnt[ex], __popcll(mask));
        base = __shfl(base, leader);
        list[ex * T_TOK + base + rank] = pid;
      }
    }
  }
}

// ------- transpose+convert: src[e][K][N] fp32 -> dst[e][N][K] bf16 ----------
__global__ __launch_bounds__(256) void transpose_convert(
    const float* __restrict__ src, unsigned short* __restrict__ dst, int K, int N) {
  __shared__ float t[128][65];
  const int e = blockIdx.x, kt = blockIdx.y, nt = blockIdx.z;
  const float* s = src + (size_t)e * K * N + (size_t)(kt * 128) * N + nt * 64;
  unsigned short* d = dst + (size_t)e * N * K + (size_t)(nt * 64) * K + kt * 128;
  const int tid = threadIdx.x;
  const int lr = tid & 15, row = tid >> 4;
#pragma unroll
  for (int p = 0; p < 8; ++p) {
    int k = row + p * 16;
    float4 v = *(const float4*)(s + (size_t)k * N + lr * 4);
    t[k][lr * 4 + 0] = v.x;
    t[k][lr * 4 + 1] = v.y;
    t[k][lr * 4 + 2] = v.z;
    t[k][lr * 4 + 3] = v.w;
  }
  __syncthreads();
  const int kc = tid & 15, nr = tid >> 4;
#pragma unroll
  for (int p = 0; p < 4; ++p) {
    int n = nr + p * 16;
    short8 o;
#pragma unroll
    for (int j = 0; j < 8; ++j) o[j] = (short)f2bf(t[kc * 8 + j][n]);
    *(short8*)&d[(size_t)n * K + kc * 8] = o;
  }
}

// ------- GEMM A: h = w * silu(x@Wg) * (x@Wu), grouped by expert -------------
// 128x64 tile, BK=32, depth-2 dbuf (33.8KB -> 4 blocks/CU), SINGLE barrier
// per K-step: VMCNT0 -> BAR -> STAGE(next, post-BAR safe) -> reads -> MFMA.
// Plain n-major grid (implicit per-XCD n-slice L2 fit). grid (I/64, E*128).
__global__ __launch_bounds__(256, 3) void gemm_gateup(
    const unsigned short* __restrict__ xb, const unsigned short* __restrict__ wgt,
    const unsigned short* __restrict__ wut, const int* __restrict__ list,
    const int* __restrict__ cnt, const float* __restrict__ pwv,
    unsigned short* __restrict__ hbuf) {
  __shared__ unsigned short As[2][128 * 32];
  __shared__ unsigned short Bg[2][64 * 32];
  __shared__ unsigned short Bu[2][64 * 32];
  __shared__ int rows_s[128];
  __shared__ float pws[128];

  const int tid = threadIdx.x;
  const int e = blockIdx.y >> 7;
  const int mt = blockIdx.y & 127;
  const int ce = cnt[e];
  if (mt * 128 >= ce) return;
  const int n0 = blockIdx.x * 64;

  if (tid < 128) {
    int idx = mt * 128 + tid;
    int pid = list[e * T_TOK + (idx < ce ? idx : 0)];
    rows_s[tid] = pid;
    pws[tid] = pwv[pid];
  }
  __syncthreads();

  const int s0 = tid, s1 = 256 + tid;
  const int q0 = (((s0 & 3) ^ ((s0 >> 3) & 3)) * 8);
  const int q1 = (((s1 & 3) ^ ((s1 >> 3) & 3)) * 8);
  const int tok0 = rows_s[s0 >> 2] >> 1, tok1 = rows_s[s1 >> 2] >> 1;

  const unsigned short* wg_base = wgt + ((size_t)e * I_DIM + n0) * H_DIM;
  const unsigned short* wu_base = wut + ((size_t)e * I_DIM + n0) * H_DIM;
  const unsigned short* a_src0 = xb + (size_t)tok0 * H_DIM + q0;
  const unsigned short* a_src1 = xb + (size_t)tok1 * H_DIM + q1;
  const unsigned short* g_src0 = wg_base + (size_t)(s0 >> 2) * H_DIM + q0;
  const unsigned short* u_src0 = wu_base + (size_t)(s0 >> 2) * H_DIM + q0;

#define STAGE_GU(b, k0)                         \
  do {                                          \
    gload16(a_src0 + (k0), &As[b][s0 * 8]);     \
    gload16(a_src1 + (k0), &As[b][s1 * 8]);     \
    gload16(g_src0 + (k0), &Bg[b][s0 * 8]);     \
    gload16(u_src0 + (k0), &Bu[b][s0 * 8]);     \
  } while (0)

  f32x4 zero = {0.f, 0.f, 0.f, 0.f};
  f32x4 accg[4][2], accu[4][2];
#pragma unroll
  for (int m = 0; m < 4; ++m)
#pragma unroll
    for (int n = 0; n < 2; ++n) { accg[m][n] = zero; accu[m][n] = zero; }

  const int lane = tid & 63;
  const int wv = tid >> 6;
  const int wr = (wv >> 1) * 64;
  const int wc = (wv & 1) * 32;
  const int lr = lane & 15;
  const int lks = (((lane >> 4) ^ ((lr >> 1) & 3)) * 8);

  STAGE_GU(0, 0);

  for (int kt = 0; kt < H_DIM / 32; ++kt) {
    const int cur = kt & 1;
    VMCNT0();  // stage(kt) landed (only batch in flight)
    BAR();     // all waves done with iter kt-1 -> safe to overwrite buf cur^1
    SCHEDFENCE();
    if (kt < H_DIM / 32 - 1) STAGE_GU(cur ^ 1, (kt + 1) * 32);
    const unsigned short* Ab = As[cur];
    const unsigned short* Bgb = Bg[cur];
    const unsigned short* Bub = Bu[cur];
    short8 a[4], bg[2], bu[2];
#pragma unroll
    for (int m = 0; m < 4; ++m)
      a[m] = *(const short8*)&Ab[(wr + m * 16 + lr) * 32 + lks];
#pragma unroll
    for (int n = 0; n < 2; ++n) {
      bg[n] = *(const short8*)&Bgb[(wc + n * 16 + lr) * 32 + lks];
      bu[n] = *(const short8*)&Bub[(wc + n * 16 + lr) * 32 + lks];
    }
    PRIO1();
#pragma unroll
    for (int m = 0; m < 4; ++m)
#pragma unroll
      for (int n = 0; n < 2; ++n) {
        accg[m][n] = __builtin_amdgcn_mfma_f32_16x16x32_bf16(a[m], bg[n], accg[m][n], 0, 0, 0);
        accu[m][n] = __builtin_amdgcn_mfma_f32_16x16x32_bf16(a[m], bu[n], accu[m][n], 0, 0, 0);
      }
    PRIO0();
  }
#undef STAGE_GU

  const int rr = (lane >> 4) * 4;
#pragma unroll
  for (int m = 0; m < 4; ++m) {
#pragma unroll
    for (int j = 0; j < 4; ++j) {
      int tr = wr + m * 16 + rr + j;
      if (mt * 128 + tr < ce) {
        int pid = rows_s[tr];
        float wgt_r = pws[tr];
        size_t rowb = (size_t)pid * I_DIM + n0 + wc;
#pragma unroll
        for (int n = 0; n < 2; ++n) {
          float g = accg[m][n][j];
          float u = accu[m][n][j];
          float hv = wgt_r * (g / (1.f + __expf(-g))) * u;
          hbuf[rowb + n * 16 + lr] = f2bf(hv);
        }
      }
    }
  }
}

// ---------------- GEMM B: pbuf[pid] = h[pid] @ Wd, grouped by expert --------
// 128x128 tile, BK=32, 3-deep LDS ring, counted vmcnt, chunked XCD remap.
// grid (H/128, E*128)  [R16/R17 proven]
__global__ __launch_bounds__(256, 3) void gemm_down(
    const unsigned short* __restrict__ hbuf, const unsigned short* __restrict__ wdt,
    const int* __restrict__ list, const int* __restrict__ cnt,
    unsigned short* __restrict__ pbuf) {
  __shared__ unsigned short As[3][128 * 32];
  __shared__ unsigned short Bs[3][128 * 32];
  __shared__ int rows_s[128];

  const int tid = threadIdx.x;
  const int flat = blockIdx.x + 8 * blockIdx.y;
  const int sw = (flat & 7) * (8192 / 8) + (flat >> 3);
  const int ntile = sw & 7;
  const int mb = sw >> 3;
  const int e = mb >> 7;
  const int mt = mb & 127;
  const int ce = cnt[e];
  if (mt * 128 >= ce) return;
  const int n0 = ntile * 128;

  if (tid < 128) {
    int idx = mt * 128 + tid;
    rows_s[tid] = list[e * T_TOK + (idx < ce ? idx : 0)];
  }
  __syncthreads();

  const int s0 = tid, s1 = 256 + tid;
  const int r0s = s0 >> 2, r1s = s1 >> 2;
  const int q0 = (((s0 & 3) ^ ((s0 >> 3) & 3)) * 8);
  const int q1 = (((s1 & 3) ^ ((s1 >> 3) & 3)) * 8);
  const int pid0 = rows_s[r0s], pid1 = rows_s[r1s];

  const unsigned short* wd_base = wdt + ((size_t)e * H_DIM + n0) * I_DIM;
  const unsigned short* a_src0 = hbuf + (size_t)pid0 * I_DIM + q0;
  const unsigned short* a_src1 = hbuf + (size_t)pid1 * I_DIM + q1;
  const unsigned short* b_src0 = wd_base + (size_t)r0s * I_DIM + q0;
  const unsigned short* b_src1 = wd_base + (size_t)r1s * I_DIM + q1;

#define STAGE_DN(b, k0)                         \
  do {                                          \
    gload16(a_src0 + (k0), &As[b][s0 * 8]);     \
    gload16(a_src1 + (k0), &As[b][s1 * 8]);     \
    gload16(b_src0 + (k0), &Bs[b][s0 * 8]);     \
    gload16(b_src1 + (k0), &Bs[b][s1 * 8]);     \
  } while (0)

  f32x4 zero = {0.f, 0.f, 0.f, 0.f};
  f32x4 acc[4][4];
#pragma unroll
  for (int m = 0; m < 4; ++m)
#pragma unroll
    for (int n = 0; n < 4; ++n) acc[m][n] = zero;

  const int lane = tid & 63;
  const int wv = tid >> 6;
  const int wr = (wv >> 1) * 64;
  const int wc = (wv & 1) * 64;
  const int lr = lane & 15;
  const int lks = (((lane >> 4) ^ ((lr >> 1) & 3)) * 8);

  STAGE_DN(0, 0);
  STAGE_DN(1, 32);

  int rb = 0;
  for (int kt = 0; kt < I_DIM / 32; ++kt) {
    if (kt < I_DIM / 32 - 1) VMCNT4(); else VMCNT0();
    BAR();
    SCHEDFENCE();
    if (kt + 2 < I_DIM / 32) {
      int sb = rb + 2; if (sb >= 3) sb -= 3;
      STAGE_DN(sb, (kt + 2) * 32);
    }
    const unsigned short* Ab = As[rb];
    const unsigned short* Bb = Bs[rb];
    short8 a[4], b[4];
#pragma unroll
    for (int m = 0; m < 4; ++m)
      a[m] = *(const short8*)&Ab[(wr + m * 16 + lr) * 32 + lks];
#pragma unroll
    for (int n = 0; n < 4; ++n)
      b[n] = *(const short8*)&Bb[(wc + n * 16 + lr) * 32 + lks];
    PRIO1();
#pragma unroll
    for (int m = 0; m < 4; ++m)
#pragma unroll
      for (int n = 0; n < 4; ++n)
        acc[m][n] = __builtin_amdgcn_mfma_f32_16x16x32_bf16(a[m], b[n], acc[m][n], 0, 0, 0);
    PRIO0();
    rb = (rb + 1 == 3) ? 0 : rb + 1;
  }
#undef STAGE_DN

  const int rr = (lane >> 4) * 4;
#pragma unroll
  for (int m = 0; m < 4; ++m) {
#pragma unroll
    for (int j = 0; j < 4; ++j) {
      int tr = wr + m * 16 + rr + j;
      if (mt * 128 + tr < ce) {
        int pid = rows_s[tr];
        unsigned short* orow = pbuf + (size_t)pid * H_DIM + n0 + wc;
#pragma unroll
        for (int n = 0; n < 4; ++n)
          orow[n * 16 + lr] = f2bf(acc[m][n][j]);
      }
    }
  }
}

// ---- combine: out[t] = pair[2t] + pair[2t+1], in-place bf16->fp32 ----------
__global__ __launch_bounds__(256) void combine_kernel(float* __restrict__ out) {
  const int tid = threadIdx.x, lane = tid & 63, wv = tid >> 6;
  const int t = blockIdx.x * 4 + wv;
  const unsigned short* p = (const unsigned short*)out;
  const unsigned short* r0 = p + (size_t)(2 * t) * H_DIM + lane * 16;
  const unsigned short* r1 = p + (size_t)(2 * t + 1) * H_DIM + lane * 16;
  short8 a0 = *(const short8*)r0;
  short8 a1 = *(const short8*)(r0 + 8);
  short8 b0 = *(const short8*)r1;
  short8 b1 = *(const short8*)(r1 + 8);
  float res[16];
#pragma unroll
  for (int j = 0; j < 8; ++j) {
    res[j] = bf2f((unsigned short)a0[j]) + bf2f((unsigned short)b0[j]);
    res[8 + j] = bf2f((unsigned short)a1[j]) + bf2f((unsigned short)b1[j]);
  }
  float* orow = out + (size_t)t * H_DIM + lane * 16;
#pragma unroll
  for (int j = 0; j < 4; ++j) {
    float4 w = {res[4 * j], res[4 * j + 1], res[4 * j + 2], res[4 * j + 3]};
    ((float4*)orow)[j] = w;
  }
}

// ---------------- launch ----------------
extern "C" void kernel_launch(void* const* d_in, const int* in_sizes, int n_in,
                              void* d_out, int out_size, void* d_ws, size_t ws_size,
                              hipStream_t stream) {
  const float* x = (const float*)d_in[0];
  const float* gw = (const float*)d_in[1];
  const float* wgf = (const float*)d_in[2];
  const float* wuf = (const float*)d_in[3];
  const float* wdf = (const float*)d_in[4];

  const size_t off_xb   = 0;
  const size_t off_wdt  = 33554432;
  const size_t off_h    = 67108864;
  const size_t off_list = 201326592;
  const size_t off_pw   = 201850880;
  const size_t off_cnt  = 201981952;
  const size_t ws_needed = off_cnt + 64;
  if (ws_size < ws_needed) return;

  char* ws = (char*)d_ws;
  unsigned short* xb   = (unsigned short*)(ws + off_xb);
  unsigned short* wdt  = (unsigned short*)(ws + off_wdt);
  unsigned short* hbuf = (unsigned short*)(ws + off_h);
  int*   list = (int*)(ws + off_list);
  float* pwv  = (float*)(ws + off_pw);
  int*   cnt  = (int*)(ws + off_cnt);
  int*   tke  = (int*)(ws + off_h);  // parks in hbuf (unused until gemm_gateup)

  unsigned short* wgt = (unsigned short*)d_out;
  unsigned short* wut = (unsigned short*)d_out + (size_t)E_NUM * H_DIM * I_DIM;
  unsigned short* pbuf = (unsigned short*)d_out;

  hipMemsetAsync(cnt, 0, E_NUM * sizeof(int), stream);

  convert_router_kernel<<<T_TOK / 4, 256, 0, stream>>>(x, gw, xb, tke, pwv);
  build_lists_kernel<<<T_TOK / 256, 256, 0, stream>>>(tke, list, cnt);
  transpose_convert<<<dim3(E_NUM, H_DIM / 128, I_DIM / 64), 256, 0, stream>>>(
      wgf, wgt, H_DIM, I_DIM);
  transpose_convert<<<dim3(E_NUM, H_DIM / 128, I_DIM / 64), 256, 0, stream>>>(
      wuf, wut, H_DIM, I_DIM);
  transpose_convert<<<dim3(E_NUM, I_DIM / 128, H_DIM / 64), 256, 0, stream>>>(
      wdf, wdt, I_DIM, H_DIM);

  gemm_gateup<<<dim3(I_DIM / 64, E_NUM * 128), 256, 0, stream>>>(
      xb, wgt, wut, list, cnt, pwv, hbuf);

  gemm_down<<<dim3(H_DIM / 128, E_NUM * 128), 256, 0, stream>>>(
      hbuf, wdt, list, cnt, pbuf);

  combine_kernel<<<T_TOK / 4, 256, 0, stream>>>((float*)d_out);
}